// Round 18
// baseline (157.867 us; speedup 1.0000x reference)
//
#include <hip/hip_runtime.h>
#include <hip/hip_bf16.h>

typedef __attribute__((ext_vector_type(4))) float f32x4;
typedef __attribute__((ext_vector_type(8))) short bf16x8;

#define NB 8
#define NS 512
#define NH 16
#define ND 64
#define HID 1024
#define NBH (NB*NH)   // 128
#define NROWS (NB*NS) // 4096

// Raw barrier WITHOUT vmcnt drain (T4): waits only on LDS ops, so global
// stores stay in flight across the barrier. "memory" clobber = compiler
// fence (no LDS op reordering across it). All cross-wave data here flows
// through LDS (lgkm) — global stores are never read in-kernel.
#define BARRIER_LGKM() asm volatile("s_waitcnt lgkmcnt(0)\n\ts_barrier" ::: "memory")

static __device__ __forceinline__ ushort f2bf(float x){
    union{float f; unsigned u;} a; a.f = x;
    unsigned r = a.u + 0x7fffu + ((a.u >> 16) & 1u);
    return (ushort)(r >> 16);
}
static __device__ __forceinline__ float bf2f(ushort x){
    union{unsigned u; float f;} a; a.u = ((unsigned)x) << 16;
    return a.f;
}

// 8 f32 -> 8 bf16 (RNE) via v_cvt_pk_bf16_f32 (no builtin on gfx950; T12).
static __device__ __forceinline__ bf16x8 cvt8(const float4 a, const float4 b){
    union { bf16x8 v; unsigned u[4]; } r;
    asm volatile("v_cvt_pk_bf16_f32 %0, %1, %2" : "=v"(r.u[0]) : "v"(a.x), "v"(a.y));
    asm volatile("v_cvt_pk_bf16_f32 %0, %1, %2" : "=v"(r.u[1]) : "v"(a.z), "v"(a.w));
    asm volatile("v_cvt_pk_bf16_f32 %0, %1, %2" : "=v"(r.u[2]) : "v"(b.x), "v"(b.y));
    asm volatile("v_cvt_pk_bf16_f32 %0, %1, %2" : "=v"(r.u[3]) : "v"(b.z), "v"(b.w));
    return r.v;
}

// ---------------- kernel 1: sinusoidal rel table (255x64, padded to 256) ---
// row 255 and tabT col 255 are EXACT ZERO (fused_attn relies on it).
__global__ void build_tables(ushort* __restrict__ tab, ushort* __restrict__ tabT){
    int t = blockIdx.x * blockDim.x + threadIdx.x;
    if (t >= 256 * 64) return;
    int p = t >> 6, d = t & 63;
    float val = 0.f;
    if (p < 255){
        int i = d >> 1;
        float angle = (float)p / powf(10000.f, (float)i / 32.f);
        val = (d & 1) ? cosf(angle) : sinf(angle);
    }
    ushort b = f2bf(val);
    tab[p * 64 + d]  = b;
    tabT[d * 256 + p] = b;
}

// ---------------- kernel 3: merged QKV projection GEMM, F32-IN ------------
// r15 structure; barriers are lgkm-only so compiler-hoisted next-step f32
// loads stay in flight across them (T4). Swizzle algebra unchanged.
__global__ __launch_bounds__(256) void proj_gemm_qkv(
    const float* __restrict__ X,
    const float* __restrict__ Wqp, const float* __restrict__ Wkp, const float* __restrict__ Wvp,
    const float* __restrict__ bqp, const float* __restrict__ bkp, const float* __restrict__ bvp,
    ushort* __restrict__ outQ, ushort* __restrict__ outK, ushort* __restrict__ outV)
{
    __shared__ ushort lA[128][64];
    __shared__ ushort lB[128][64];
    int sel = blockIdx.x >> 3;
    const float* W    = sel == 0 ? Wqp : (sel == 1 ? Wkp : Wvp);
    const float* bias = sel == 0 ? bqp : (sel == 1 ? bkp : bvp);
    ushort* out       = sel == 0 ? outQ : (sel == 1 ? outK : outV);
    int n0 = (blockIdx.x & 7) * 128;
    int m0 = blockIdx.y * 128;
    int tid = threadIdx.x;
    int wave = tid >> 6, lane = tid & 63;
    int wr = (wave >> 1) * 64, wc = (wave & 1) * 64;
    int lrow = lane & 15, g = lane >> 4;

    const int srow = tid >> 3;                        // staging row (+p*32)
    const int gcol = ((tid & 7) ^ (srow & 7)) * 8;    // global element offset
    const int lcol = (tid & 7) * 8;                   // LDS element offset
    const int sw = lrow & 7;

    f32x4 acc[4][4] = {};

    for (int k0 = 0; k0 < HID; k0 += 64){
        BARRIER_LGKM();
        #pragma unroll
        for (int p = 0; p < 4; ++p){
            const float* xs = &X[(size_t)(m0 + srow + p*32) * HID + k0 + gcol];
            float4 xa = *reinterpret_cast<const float4*>(xs);
            float4 xb = *reinterpret_cast<const float4*>(xs + 4);
            const float* wsrc = &W[(size_t)(n0 + srow + p*32) * HID + k0 + gcol];
            float4 wa = *reinterpret_cast<const float4*>(wsrc);
            float4 wb = *reinterpret_cast<const float4*>(wsrc + 4);
            *reinterpret_cast<bf16x8*>(&lA[srow + p*32][lcol]) = cvt8(xa, xb);
            *reinterpret_cast<bf16x8*>(&lB[srow + p*32][lcol]) = cvt8(wa, wb);
        }
        BARRIER_LGKM();
        #pragma unroll
        for (int ks = 0; ks < 2; ++ks){
            bf16x8 af[4], bfr[4];
            #pragma unroll
            for (int m = 0; m < 4; ++m)
                af[m] = *reinterpret_cast<const bf16x8*>(
                    &lA[wr + m*16 + lrow][(((ks*4 + g) ^ sw)) * 8]);
            #pragma unroll
            for (int n = 0; n < 4; ++n)
                bfr[n] = *reinterpret_cast<const bf16x8*>(
                    &lB[wc + n*16 + lrow][(((ks*4 + g) ^ sw)) * 8]);
            #pragma unroll
            for (int m = 0; m < 4; ++m)
                #pragma unroll
                for (int n = 0; n < 4; ++n)
                    acc[m][n] = __builtin_amdgcn_mfma_f32_16x16x32_bf16(af[m], bfr[n], acc[m][n], 0, 0, 0);
        }
    }

    #pragma unroll
    for (int m = 0; m < 4; ++m){
        #pragma unroll
        for (int n = 0; n < 4; ++n){
            int col = n0 + wc + n*16 + lrow;
            float bv = bias[col];
            int h = col >> 6, d = col & 63;
            #pragma unroll
            for (int r = 0; r < 4; ++r){
                int mg = m0 + wr + m*16 + (lane >> 4)*4 + r;
                int b = mg >> 9, s = mg & 511;
                float val = acc[m][n][r] + bv;
                if (sel != 2)
                    out[(((size_t)(b*NH + h))*NS + s)*ND + d] = f2bf(val);
                else
                    out[(((size_t)(b*NH + h))*ND + d)*NS + s] = f2bf(val);
            }
        }
    }
}

// ---------------- kernel 4: fused scores+softmax+PV+P.rel -----------------
// r12 best + T4 lgkm-only barriers: scores stores (8 KB/wave) no longer
// drain at the C-end barrier — they stay in flight through phases F and G
// and drain at endpgm. ~3x longer write-concurrency window attacks the
// 1.4 TB/s write-drain cap that has pinned this kernel at ~108 us.
// UNNORMALIZED-P; swapped QK^T; no max subtraction; qq[] = qrel then pbar;
// stale bin 255 multiplies tabT col 255 == 0.
__global__ __launch_bounds__(256, 6) void fused_attn(
    const ushort* __restrict__ Qb, const ushort* __restrict__ Kb,
    const ushort* __restrict__ vT, const ushort* __restrict__ tab,
    const ushort* __restrict__ tabT, const float* __restrict__ mask,
    float* __restrict__ scores, float* __restrict__ ctx)
{
    __shared__ ushort pL[16][512];
    __shared__ ushort qq[16][256];
    __shared__ float  rsum[16][4];
    __shared__ float  rleft[16][4];
    __shared__ float  rright[16][4];
    ushort* pLf = &pL[0][0];
    ushort* qqf = &qq[0][0];
#define SWZ(row, col) ((col) ^ (((row)&7)<<3))

    const int bh = blockIdx.x;
    const int b = bh >> 4, h = bh & 15;
    const int q0 = blockIdx.y * 16;
    const int wave = threadIdx.x >> 6, lane = threadIdx.x & 63;
    const int lrow = lane & 15, g = lane >> 4, lk8 = g * 8;

    const ushort* Qh = Qb + (size_t)bh * NS * ND;
    const ushort* Kh = Kb + (size_t)bh * NS * ND;
    const int q = q0 + lrow;

    bf16x8 qf0 = *reinterpret_cast<const bf16x8*>(&Qh[(size_t)(q0 + lrow)*ND + lk8]);
    bf16x8 qf1 = *reinterpret_cast<const bf16x8*>(&Qh[(size_t)(q0 + lrow)*ND + 32 + lk8]);

    // ---- phase A1: table-part QK^T + stash qrel ----
    #pragma unroll
    for (int t = 0; t < 4; ++t){
        const ushort* src = &tab[(size_t)(wave*64 + t*16 + lrow)*ND];
        bf16x8 k0v = *reinterpret_cast<const bf16x8*>(&src[lk8]);
        bf16x8 k1v = *reinterpret_cast<const bf16x8*>(&src[32 + lk8]);
        f32x4 at = __builtin_amdgcn_mfma_f32_16x16x32_bf16(k0v, qf0, (f32x4){0.f,0.f,0.f,0.f}, 0, 0, 0);
        at = __builtin_amdgcn_mfma_f32_16x16x32_bf16(k1v, qf1, at, 0, 0, 0);
        ushort4 w;
        w.x = f2bf(at[0]); w.y = f2bf(at[1]); w.z = f2bf(at[2]); w.w = f2bf(at[3]);
        int col = wave*64 + t*16 + g*4;
        *reinterpret_cast<ushort4*>(&qqf[lrow*256 + SWZ(lrow, col)]) = w;
    }
    BARRIER_LGKM();

    // ---- phase C: K-part QK^T (K prefetched 1 ahead); scores; e->pL ----
    float st = 0.f, sl = 0.f, sr = 0.f;
    const float* maskb = &mask[b*NS];
    float* srow = &scores[((size_t)bh*NS + q)*NS];
    const ushort* srcK0 = &Kh[(size_t)(wave*128 + lrow)*ND];
    bf16x8 ka = *reinterpret_cast<const bf16x8*>(&srcK0[lk8]);
    bf16x8 kb = *reinterpret_cast<const bf16x8*>(&srcK0[32 + lk8]);
    #pragma unroll
    for (int n = 0; n < 8; ++n){
        bf16x8 ka1, kb1;
        if (n < 7){
            const ushort* s1 = &Kh[(size_t)(wave*128 + (n+1)*16 + lrow)*ND];
            ka1 = *reinterpret_cast<const bf16x8*>(&s1[lk8]);
            kb1 = *reinterpret_cast<const bf16x8*>(&s1[32 + lk8]);
        }
        int kbase = wave*128 + n*16 + g*4;
        f32x4 a = __builtin_amdgcn_mfma_f32_16x16x32_bf16(ka, qf0, (f32x4){0.f,0.f,0.f,0.f}, 0, 0, 0);
        a = __builtin_amdgcn_mfma_f32_16x16x32_bf16(kb, qf1, a, 0, 0, 0);
        float4 mk4 = *reinterpret_cast<const float4*>(&maskb[kbase]);
        float mk[4] = {mk4.x, mk4.y, mk4.z, mk4.w};
        f32x4 sv;
        ushort4 pw;
        #pragma unroll
        for (int r = 0; r < 4; ++r){
            int k = kbase + r;
            int dd = min(127, max(-127, k - q));
            float val = (a[r] + bf2f(qqf[lrow*256 + SWZ(lrow, dd + 127)])) * 0.125f + mk[r];
            sv[r] = val;
            float e = __expf(val);
            st += e;
            if (k <= q - 127) sl += e;
            if (k >= q + 127) sr += e;
            ((ushort*)&pw)[r] = f2bf(e);
        }
        *reinterpret_cast<f32x4*>(&srow[kbase]) = sv;
        *reinterpret_cast<ushort4*>(&pLf[lrow*512 + SWZ(lrow, kbase)]) = pw;
        ka = ka1; kb = kb1;
    }
    st += __shfl_xor(st, 16); st += __shfl_xor(st, 32);
    sl += __shfl_xor(sl, 16); sl += __shfl_xor(sl, 32);
    sr += __shfl_xor(sr, 16); sr += __shfl_xor(sr, 32);
    if (lane < 16){
        rsum[lrow][wave]   = st;
        rleft[lrow][wave]  = sl;
        rright[lrow][wave] = sr;
    }
    BARRIER_LGKM();   // stores stay in flight past here (T4)

    // ---- phase F: pbar bins (unnormalized) ----
    if (wave == 0 && lane < 16){
        float SL = rleft[lrow][0] + rleft[lrow][1] + rleft[lrow][2] + rleft[lrow][3];
        float SR = rright[lrow][0] + rright[lrow][1] + rright[lrow][2] + rright[lrow][3];
        qqf[lrow*256 + SWZ(lrow, 0)]   = f2bf(SL);
        qqf[lrow*256 + SWZ(lrow, 254)] = f2bf(SR);
    }
    for (int idx = threadIdx.x; idx < 16*256; idx += 256){
        int row = idx >> 8, j = idx & 255;
        if (j == 0 || j >= 254) continue;
        int col = q0 + row + j - 127;
        qqf[row*256 + SWZ(row, j)] =
            (col >= 0 && col < NS) ? pLf[row*512 + SWZ(row, col)] : (ushort)0;
    }
    BARRIER_LGKM();

    // ---- phase G: ctx = (E·V + ebar·table) / T ----
    const int d = wave*16 + lrow;
    const ushort* vTh = vT + ((size_t)bh*ND + d)*NS;
    const ushort* tTd = tabT + (size_t)d*256;
    f32x4 o0 = (f32x4){0.f,0.f,0.f,0.f};
    f32x4 o1 = (f32x4){0.f,0.f,0.f,0.f};
    __builtin_amdgcn_s_setprio(1);
    #pragma unroll
    for (int k0 = 0; k0 < NS; k0 += 64){
        bf16x8 bv0 = *reinterpret_cast<const bf16x8*>(&vTh[k0 + lk8]);
        bf16x8 pa0 = *reinterpret_cast<const bf16x8*>(&pLf[lrow*512 + SWZ(lrow, k0 + lk8)]);
        o0 = __builtin_amdgcn_mfma_f32_16x16x32_bf16(pa0, bv0, o0, 0, 0, 0);
        bf16x8 bv1 = *reinterpret_cast<const bf16x8*>(&vTh[k0 + 32 + lk8]);
        bf16x8 pa1 = *reinterpret_cast<const bf16x8*>(&pLf[lrow*512 + SWZ(lrow, k0 + 32 + lk8)]);
        o1 = __builtin_amdgcn_mfma_f32_16x16x32_bf16(pa1, bv1, o1, 0, 0, 0);
    }
    #pragma unroll
    for (int k0 = 0; k0 < 256; k0 += 64){
        bf16x8 bv0 = *reinterpret_cast<const bf16x8*>(&tTd[k0 + lk8]);
        bf16x8 pa0 = *reinterpret_cast<const bf16x8*>(&qqf[lrow*256 + SWZ(lrow, k0 + lk8)]);
        o0 = __builtin_amdgcn_mfma_f32_16x16x32_bf16(pa0, bv0, o0, 0, 0, 0);
        bf16x8 bv1 = *reinterpret_cast<const bf16x8*>(&tTd[k0 + 32 + lk8]);
        bf16x8 pa1 = *reinterpret_cast<const bf16x8*>(&qqf[lrow*256 + SWZ(lrow, k0 + 32 + lk8)]);
        o1 = __builtin_amdgcn_mfma_f32_16x16x32_bf16(pa1, bv1, o1, 0, 0, 0);
    }
    __builtin_amdgcn_s_setprio(0);
    #pragma unroll
    for (int r = 0; r < 4; ++r){
        int row = g*4 + r;
        float T = rsum[row][0] + rsum[row][1] + rsum[row][2] + rsum[row][3];
        int qo = q0 + row;
        ctx[((size_t)b*NS + qo)*HID + h*ND + d] = (o0[r] + o1[r]) * (1.f / T);
    }
#undef SWZ
}

extern "C" void kernel_launch(void* const* d_in, const int* in_sizes, int n_in,
                              void* d_out, int out_size, void* d_ws, size_t ws_size,
                              hipStream_t stream)
{
    const float* x    = (const float*)d_in[0];
    const float* mask = (const float*)d_in[1];
    const float* Wq   = (const float*)d_in[2];
    const float* bq   = (const float*)d_in[3];
    const float* Wk   = (const float*)d_in[4];
    const float* bk   = (const float*)d_in[5];
    const float* Wv   = (const float*)d_in[6];
    const float* bv   = (const float*)d_in[7];

    float* out = (float*)d_out;
    float* ctx    = out;                      // [8][512][1024]
    float* scores = out + (size_t)NB*NS*HID;  // [8][16][512][512]

    char* ws = (char*)d_ws;
    ushort* q_bf  = (ushort*)ws;  ws += (size_t)NBH*NS*ND*2;
    ushort* k_bf  = (ushort*)ws;  ws += (size_t)NBH*NS*ND*2;
    ushort* vT_bf = (ushort*)ws;  ws += (size_t)NBH*NS*ND*2;
    ushort* tab   = (ushort*)ws;  ws += 256*64*2;
    ushort* tabT  = (ushort*)ws;  ws += 64*256*2;

    build_tables<<<64, 256, 0, stream>>>(tab, tabT);

    proj_gemm_qkv<<<dim3(24, 32), 256, 0, stream>>>(
        x, Wq, Wk, Wv, bq, bk, bv, q_bf, k_bf, vT_bf);

    fused_attn<<<dim3(NBH, NS/16), 256, 0, stream>>>(
        q_bf, k_bf, vT_bf, tab, tabT, mask, scores, ctx);
}

// Round 19
// 157.276 us; speedup vs baseline: 1.0038x; 1.0038x over previous
//
#include <hip/hip_runtime.h>
#include <hip/hip_bf16.h>

typedef __attribute__((ext_vector_type(4))) float f32x4;
typedef __attribute__((ext_vector_type(8))) short bf16x8;

#define NB 8
#define NS 512
#define NH 16
#define ND 64
#define HID 1024
#define NBH (NB*NH)   // 128
#define NROWS (NB*NS) // 4096

static __device__ __forceinline__ ushort f2bf(float x){
    union{float f; unsigned u;} a; a.f = x;
    unsigned r = a.u + 0x7fffu + ((a.u >> 16) & 1u);
    return (ushort)(r >> 16);
}
static __device__ __forceinline__ float bf2f(ushort x){
    union{unsigned u; float f;} a; a.u = ((unsigned)x) << 16;
    return a.f;
}

// 8 f32 -> 8 bf16 (RNE) via v_cvt_pk_bf16_f32 (no builtin on gfx950; T12).
static __device__ __forceinline__ bf16x8 cvt8(const float4 a, const float4 b){
    union { bf16x8 v; unsigned u[4]; } r;
    asm volatile("v_cvt_pk_bf16_f32 %0, %1, %2" : "=v"(r.u[0]) : "v"(a.x), "v"(a.y));
    asm volatile("v_cvt_pk_bf16_f32 %0, %1, %2" : "=v"(r.u[1]) : "v"(a.z), "v"(a.w));
    asm volatile("v_cvt_pk_bf16_f32 %0, %1, %2" : "=v"(r.u[2]) : "v"(b.x), "v"(b.y));
    asm volatile("v_cvt_pk_bf16_f32 %0, %1, %2" : "=v"(r.u[3]) : "v"(b.z), "v"(b.w));
    return r.v;
}

// ---------------- kernel 1: sinusoidal rel table (255x64, padded to 256) ---
// row 255 and tabT col 255 are EXACT ZERO (fused_attn relies on it).
__global__ void build_tables(ushort* __restrict__ tab, ushort* __restrict__ tabT){
    int t = blockIdx.x * blockDim.x + threadIdx.x;
    if (t >= 256 * 64) return;
    int p = t >> 6, d = t & 63;
    float val = 0.f;
    if (p < 255){
        int i = d >> 1;
        float angle = (float)p / powf(10000.f, (float)i / 32.f);
        val = (d & 1) ? cosf(angle) : sinf(angle);
    }
    ushort b = f2bf(val);
    tab[p * 64 + d]  = b;
    tabT[d * 256 + p] = b;
}

// ---------------- kernel 3: merged QKV projection GEMM, F32-IN + T1 -------
// r15 structure + XCD-aware bijective block remap (T1, nwg=768 ≡ 0 mod 8):
//   wid = y*24 + x;  rid = (wid%8)*96 + wid/8
// -> each XCD owns 4 contiguous row-blocks x all 24 (sel,col) blocks, so its
// 2 MB X panel set is L2-resident (24x reuse captured in-XCD; previously the
// 8 col-blocks sharing an X panel round-robined onto 8 different XCDs).
// Swizzle algebra / staging identical to r15 (measured best).
__global__ __launch_bounds__(256) void proj_gemm_qkv(
    const float* __restrict__ X,
    const float* __restrict__ Wqp, const float* __restrict__ Wkp, const float* __restrict__ Wvp,
    const float* __restrict__ bqp, const float* __restrict__ bkp, const float* __restrict__ bvp,
    ushort* __restrict__ outQ, ushort* __restrict__ outK, ushort* __restrict__ outV)
{
    __shared__ ushort lA[128][64];
    __shared__ ushort lB[128][64];

    // T1 bijective chunked remap (768 blocks, 8 XCDs, 96 blocks/XCD)
    int wid = blockIdx.y * 24 + blockIdx.x;
    int rid = (wid & 7) * 96 + (wid >> 3);
    int rowblk = rid / 24;
    int cc     = rid % 24;
    int sel    = cc >> 3;
    const float* W    = sel == 0 ? Wqp : (sel == 1 ? Wkp : Wvp);
    const float* bias = sel == 0 ? bqp : (sel == 1 ? bkp : bvp);
    ushort* out       = sel == 0 ? outQ : (sel == 1 ? outK : outV);
    int n0 = (cc & 7) * 128;
    int m0 = rowblk * 128;

    int tid = threadIdx.x;
    int wave = tid >> 6, lane = tid & 63;
    int wr = (wave >> 1) * 64, wc = (wave & 1) * 64;
    int lrow = lane & 15, g = lane >> 4;

    const int srow = tid >> 3;                        // staging row (+p*32)
    const int gcol = ((tid & 7) ^ (srow & 7)) * 8;    // global element offset
    const int lcol = (tid & 7) * 8;                   // LDS element offset
    const int sw = lrow & 7;

    f32x4 acc[4][4] = {};

    for (int k0 = 0; k0 < HID; k0 += 64){
        __syncthreads();
        #pragma unroll
        for (int p = 0; p < 4; ++p){
            const float* xs = &X[(size_t)(m0 + srow + p*32) * HID + k0 + gcol];
            float4 xa = *reinterpret_cast<const float4*>(xs);
            float4 xb = *reinterpret_cast<const float4*>(xs + 4);
            const float* wsrc = &W[(size_t)(n0 + srow + p*32) * HID + k0 + gcol];
            float4 wa = *reinterpret_cast<const float4*>(wsrc);
            float4 wb = *reinterpret_cast<const float4*>(wsrc + 4);
            *reinterpret_cast<bf16x8*>(&lA[srow + p*32][lcol]) = cvt8(xa, xb);
            *reinterpret_cast<bf16x8*>(&lB[srow + p*32][lcol]) = cvt8(wa, wb);
        }
        __syncthreads();
        #pragma unroll
        for (int ks = 0; ks < 2; ++ks){
            bf16x8 af[4], bfr[4];
            #pragma unroll
            for (int m = 0; m < 4; ++m)
                af[m] = *reinterpret_cast<const bf16x8*>(
                    &lA[wr + m*16 + lrow][(((ks*4 + g) ^ sw)) * 8]);
            #pragma unroll
            for (int n = 0; n < 4; ++n)
                bfr[n] = *reinterpret_cast<const bf16x8*>(
                    &lB[wc + n*16 + lrow][(((ks*4 + g) ^ sw)) * 8]);
            #pragma unroll
            for (int m = 0; m < 4; ++m)
                #pragma unroll
                for (int n = 0; n < 4; ++n)
                    acc[m][n] = __builtin_amdgcn_mfma_f32_16x16x32_bf16(af[m], bfr[n], acc[m][n], 0, 0, 0);
        }
    }

    #pragma unroll
    for (int m = 0; m < 4; ++m){
        #pragma unroll
        for (int n = 0; n < 4; ++n){
            int col = n0 + wc + n*16 + lrow;
            float bv = bias[col];
            int h = col >> 6, d = col & 63;
            #pragma unroll
            for (int r = 0; r < 4; ++r){
                int mg = m0 + wr + m*16 + (lane >> 4)*4 + r;
                int b = mg >> 9, s = mg & 511;
                float val = acc[m][n][r] + bv;
                if (sel != 2)
                    out[(((size_t)(b*NH + h))*NS + s)*ND + d] = f2bf(val);
                else
                    out[(((size_t)(b*NH + h))*ND + d)*NS + s] = f2bf(val);
            }
        }
    }
}

// ---------------- kernel 4: fused scores+softmax+PV+P.rel (r12, best) -----
// UNNORMALIZED-P: pL/pbar hold raw e=exp(s); ctx scaled by 1/T at the end.
// Swapped QK^T (lane owns one q row). No max subtraction (|s| <~ 12).
// Normal scores stores (ack at L2). qq[] = qrel in A1/C, pbar in F/G;
// stale bin 255 multiplies tabT col 255 == 0. BYTE-IDENTICAL to the
// measured-best r12/r15/r17 version — protected state.
__global__ __launch_bounds__(256, 6) void fused_attn(
    const ushort* __restrict__ Qb, const ushort* __restrict__ Kb,
    const ushort* __restrict__ vT, const ushort* __restrict__ tab,
    const ushort* __restrict__ tabT, const float* __restrict__ mask,
    float* __restrict__ scores, float* __restrict__ ctx)
{
    __shared__ ushort pL[16][512];
    __shared__ ushort qq[16][256];
    __shared__ float  rsum[16][4];
    __shared__ float  rleft[16][4];
    __shared__ float  rright[16][4];
    ushort* pLf = &pL[0][0];
    ushort* qqf = &qq[0][0];
#define SWZ(row, col) ((col) ^ (((row)&7)<<3))

    const int bh = blockIdx.x;
    const int b = bh >> 4, h = bh & 15;
    const int q0 = blockIdx.y * 16;
    const int wave = threadIdx.x >> 6, lane = threadIdx.x & 63;
    const int lrow = lane & 15, g = lane >> 4, lk8 = g * 8;

    const ushort* Qh = Qb + (size_t)bh * NS * ND;
    const ushort* Kh = Kb + (size_t)bh * NS * ND;
    const int q = q0 + lrow;

    bf16x8 qf0 = *reinterpret_cast<const bf16x8*>(&Qh[(size_t)(q0 + lrow)*ND + lk8]);
    bf16x8 qf1 = *reinterpret_cast<const bf16x8*>(&Qh[(size_t)(q0 + lrow)*ND + 32 + lk8]);

    // ---- phase A1: table-part QK^T + stash qrel ----
    #pragma unroll
    for (int t = 0; t < 4; ++t){
        const ushort* src = &tab[(size_t)(wave*64 + t*16 + lrow)*ND];
        bf16x8 k0v = *reinterpret_cast<const bf16x8*>(&src[lk8]);
        bf16x8 k1v = *reinterpret_cast<const bf16x8*>(&src[32 + lk8]);
        f32x4 at = __builtin_amdgcn_mfma_f32_16x16x32_bf16(k0v, qf0, (f32x4){0.f,0.f,0.f,0.f}, 0, 0, 0);
        at = __builtin_amdgcn_mfma_f32_16x16x32_bf16(k1v, qf1, at, 0, 0, 0);
        ushort4 w;
        w.x = f2bf(at[0]); w.y = f2bf(at[1]); w.z = f2bf(at[2]); w.w = f2bf(at[3]);
        int col = wave*64 + t*16 + g*4;
        *reinterpret_cast<ushort4*>(&qqf[lrow*256 + SWZ(lrow, col)]) = w;
    }
    __syncthreads();

    // ---- phase C: K-part QK^T (K prefetched 1 ahead); scores; e->pL ----
    float st = 0.f, sl = 0.f, sr = 0.f;
    const float* maskb = &mask[b*NS];
    float* srow = &scores[((size_t)bh*NS + q)*NS];
    const ushort* srcK0 = &Kh[(size_t)(wave*128 + lrow)*ND];
    bf16x8 ka = *reinterpret_cast<const bf16x8*>(&srcK0[lk8]);
    bf16x8 kb = *reinterpret_cast<const bf16x8*>(&srcK0[32 + lk8]);
    #pragma unroll
    for (int n = 0; n < 8; ++n){
        bf16x8 ka1, kb1;
        if (n < 7){
            const ushort* s1 = &Kh[(size_t)(wave*128 + (n+1)*16 + lrow)*ND];
            ka1 = *reinterpret_cast<const bf16x8*>(&s1[lk8]);
            kb1 = *reinterpret_cast<const bf16x8*>(&s1[32 + lk8]);
        }
        int kbase = wave*128 + n*16 + g*4;
        f32x4 a = __builtin_amdgcn_mfma_f32_16x16x32_bf16(ka, qf0, (f32x4){0.f,0.f,0.f,0.f}, 0, 0, 0);
        a = __builtin_amdgcn_mfma_f32_16x16x32_bf16(kb, qf1, a, 0, 0, 0);
        float4 mk4 = *reinterpret_cast<const float4*>(&maskb[kbase]);
        float mk[4] = {mk4.x, mk4.y, mk4.z, mk4.w};
        f32x4 sv;
        ushort4 pw;
        #pragma unroll
        for (int r = 0; r < 4; ++r){
            int k = kbase + r;
            int dd = min(127, max(-127, k - q));
            float val = (a[r] + bf2f(qqf[lrow*256 + SWZ(lrow, dd + 127)])) * 0.125f + mk[r];
            sv[r] = val;
            float e = __expf(val);
            st += e;
            if (k <= q - 127) sl += e;
            if (k >= q + 127) sr += e;
            ((ushort*)&pw)[r] = f2bf(e);
        }
        *reinterpret_cast<f32x4*>(&srow[kbase]) = sv;
        *reinterpret_cast<ushort4*>(&pLf[lrow*512 + SWZ(lrow, kbase)]) = pw;
        ka = ka1; kb = kb1;
    }
    st += __shfl_xor(st, 16); st += __shfl_xor(st, 32);
    sl += __shfl_xor(sl, 16); sl += __shfl_xor(sl, 32);
    sr += __shfl_xor(sr, 16); sr += __shfl_xor(sr, 32);
    if (lane < 16){
        rsum[lrow][wave]   = st;
        rleft[lrow][wave]  = sl;
        rright[lrow][wave] = sr;
    }
    __syncthreads();

    // ---- phase F: pbar bins (unnormalized) ----
    if (wave == 0 && lane < 16){
        float SL = rleft[lrow][0] + rleft[lrow][1] + rleft[lrow][2] + rleft[lrow][3];
        float SR = rright[lrow][0] + rright[lrow][1] + rright[lrow][2] + rright[lrow][3];
        qqf[lrow*256 + SWZ(lrow, 0)]   = f2bf(SL);
        qqf[lrow*256 + SWZ(lrow, 254)] = f2bf(SR);
    }
    for (int idx = threadIdx.x; idx < 16*256; idx += 256){
        int row = idx >> 8, j = idx & 255;
        if (j == 0 || j >= 254) continue;
        int col = q0 + row + j - 127;
        qqf[row*256 + SWZ(row, j)] =
            (col >= 0 && col < NS) ? pLf[row*512 + SWZ(row, col)] : (ushort)0;
    }
    __syncthreads();

    // ---- phase G: ctx = (E·V + ebar·table) / T ----
    const int d = wave*16 + lrow;
    const ushort* vTh = vT + ((size_t)bh*ND + d)*NS;
    const ushort* tTd = tabT + (size_t)d*256;
    f32x4 o0 = (f32x4){0.f,0.f,0.f,0.f};
    f32x4 o1 = (f32x4){0.f,0.f,0.f,0.f};
    __builtin_amdgcn_s_setprio(1);
    #pragma unroll
    for (int k0 = 0; k0 < NS; k0 += 64){
        bf16x8 bv0 = *reinterpret_cast<const bf16x8*>(&vTh[k0 + lk8]);
        bf16x8 pa0 = *reinterpret_cast<const bf16x8*>(&pLf[lrow*512 + SWZ(lrow, k0 + lk8)]);
        o0 = __builtin_amdgcn_mfma_f32_16x16x32_bf16(pa0, bv0, o0, 0, 0, 0);
        bf16x8 bv1 = *reinterpret_cast<const bf16x8*>(&vTh[k0 + 32 + lk8]);
        bf16x8 pa1 = *reinterpret_cast<const bf16x8*>(&pLf[lrow*512 + SWZ(lrow, k0 + 32 + lk8)]);
        o1 = __builtin_amdgcn_mfma_f32_16x16x32_bf16(pa1, bv1, o1, 0, 0, 0);
    }
    #pragma unroll
    for (int k0 = 0; k0 < 256; k0 += 64){
        bf16x8 bv0 = *reinterpret_cast<const bf16x8*>(&tTd[k0 + lk8]);
        bf16x8 pa0 = *reinterpret_cast<const bf16x8*>(&qqf[lrow*256 + SWZ(lrow, k0 + lk8)]);
        o0 = __builtin_amdgcn_mfma_f32_16x16x32_bf16(pa0, bv0, o0, 0, 0, 0);
        bf16x8 bv1 = *reinterpret_cast<const bf16x8*>(&tTd[k0 + 32 + lk8]);
        bf16x8 pa1 = *reinterpret_cast<const bf16x8*>(&qqf[lrow*256 + SWZ(lrow, k0 + 32 + lk8)]);
        o1 = __builtin_amdgcn_mfma_f32_16x16x32_bf16(pa1, bv1, o1, 0, 0, 0);
    }
    __builtin_amdgcn_s_setprio(0);
    #pragma unroll
    for (int r = 0; r < 4; ++r){
        int row = g*4 + r;
        float T = rsum[row][0] + rsum[row][1] + rsum[row][2] + rsum[row][3];
        int qo = q0 + row;
        ctx[((size_t)b*NS + qo)*HID + h*ND + d] = (o0[r] + o1[r]) * (1.f / T);
    }
#undef SWZ
}

extern "C" void kernel_launch(void* const* d_in, const int* in_sizes, int n_in,
                              void* d_out, int out_size, void* d_ws, size_t ws_size,
                              hipStream_t stream)
{
    const float* x    = (const float*)d_in[0];
    const float* mask = (const float*)d_in[1];
    const float* Wq   = (const float*)d_in[2];
    const float* bq   = (const float*)d_in[3];
    const float* Wk   = (const float*)d_in[4];
    const float* bk   = (const float*)d_in[5];
    const float* Wv   = (const float*)d_in[6];
    const float* bv   = (const float*)d_in[7];

    float* out = (float*)d_out;
    float* ctx    = out;                      // [8][512][1024]
    float* scores = out + (size_t)NB*NS*HID;  // [8][16][512][512]

    char* ws = (char*)d_ws;
    ushort* q_bf  = (ushort*)ws;  ws += (size_t)NBH*NS*ND*2;
    ushort* k_bf  = (ushort*)ws;  ws += (size_t)NBH*NS*ND*2;
    ushort* vT_bf = (ushort*)ws;  ws += (size_t)NBH*NS*ND*2;
    ushort* tab   = (ushort*)ws;  ws += 256*64*2;
    ushort* tabT  = (ushort*)ws;  ws += 64*256*2;

    build_tables<<<64, 256, 0, stream>>>(tab, tabT);

    proj_gemm_qkv<<<dim3(24, 32), 256, 0, stream>>>(
        x, Wq, Wk, Wv, bq, bk, bv, q_bf, k_bf, vT_bf);

    fused_attn<<<dim3(NBH, NS/16), 256, 0, stream>>>(
        q_bf, k_bf, vT_bf, tab, tabT, mask, scores, ctx);
}